// Round 3
// baseline (262.692 us; speedup 1.0000x reference)
//
#include <hip/hip_runtime.h>
#include <hip/hip_bf16.h>
#include <math.h>

// ---------------------------------------------------------------------------
// Round 3: same validated MFMA core as round 2 (absmax 0.125), restructured
// for latency/stall removal:
//   - 3 barriers/tile (was 5): S3 y1-ready, S4 y2-ready, S5 partials-ready.
//     Top-of-loop and staging barriers proven unnecessary by phase analysis.
//   - no hpS LDS staging (was the 1.2e7 bank-conflict source): phase A thread
//     owns feature octet n8=tid&15, reads hpart rows straight from global ws
//     (1.5KB/tile, L1-resident -> overlaps LDS pipe instead of loading it).
//   - epilogue: per-wave plain stores to partS4[4][64] (no LDS atomics, no
//     pre-zero barrier).
//   - grid 768 = 13056/17 exact, __launch_bounds__(256,3) -> 3 blocks/CU.
//   - hpart precompute: all 32 h rows staged once, ONE sync, ~4 us.
//   - packed bf16 convert via v_cvt_pk_bf16_f32 when available (RNE, same
//     rounding as __float2bfloat16).
// ws floats: [0..50]=cc_w  [64..114]=steps  [128]=xmax  [256..]=hpart[16384][128]
// ---------------------------------------------------------------------------

#define B_N    16384
#define KQ     51
#define HD     128
#define IND    64
#define M_TOT  (B_N * KQ)        // 835584
#define TS     64                // samples per tile
#define NTILES (M_TOT / TS)      // 13056
#define GRID_MAIN 768            // 13056 / 768 = 17 tiles/block exactly

#define WS_CCW    0
#define WS_STEPS  64
#define WS_XMAX   128
#define WS_HPART  256

typedef __attribute__((ext_vector_type(8))) short short8;
typedef __attribute__((ext_vector_type(4))) float f32x4;

__device__ __forceinline__ unsigned short f2bf(float f) {
    __hip_bfloat16 t = __float2bfloat16(f);
    return *reinterpret_cast<unsigned short*>(&t);
}

#if defined(__gfx950__) && defined(__has_builtin)
#if __has_builtin(__builtin_amdgcn_cvt_pk_bf16_f32)
#define HAVE_PK_BF16 1
#endif
#endif

__device__ __forceinline__ unsigned pk_bf16(float lo, float hi) {
#ifdef HAVE_PK_BF16
    typedef __attribute__((ext_vector_type(2))) __bf16 bfv2;
    bfv2 r = __builtin_amdgcn_cvt_pk_bf16_f32(lo, hi);
    return *reinterpret_cast<unsigned*>(&r);
#else
    return (unsigned)f2bf(lo) | ((unsigned)f2bf(hi) << 16);
#endif
}

// ---------------- prep: CC table (fp64), xmax, zero d_out -------------------
__global__ void umnn_prep(const float* __restrict__ x, float* __restrict__ out,
                          float* __restrict__ ws)
{
    const int tid = threadIdx.x;
    const int bid = blockIdx.x;
    if (bid == 0) {
        if (tid <= KQ - 1) {
            int j = tid;
            ws[WS_STEPS + j] = (float)cos((double)j * M_PI / 50.0);
            double s = 0.0;
            for (int i = 0; i <= 50; i += 2) {       // odd i have W=0
                double Wi = (i == 0) ? 1.0 : 2.0 / (1.0 - (double)(i * i));
                double lam;
                if (j == 0) lam = 0.5;
                else {
                    lam = cos((double)(i * j) * M_PI / 50.0);
                    if (j == 50) lam *= 0.5;
                }
                lam *= (2.0 / 50.0);
                s += lam * Wi;
            }
            ws[WS_CCW + j] = (float)s;
        }
    } else if (bid == 1) {
        __shared__ float red[256];
        float mx = -1e30f;
        for (int i = tid; i < B_N; i += 256) mx = fmaxf(mx, x[i]);
        red[tid] = mx;
        __syncthreads();
        for (int s2 = 128; s2 > 0; s2 >>= 1) {
            if (tid < s2) red[tid] = fmaxf(red[tid], red[tid + s2]);
            __syncthreads();
        }
        if (tid == 0) ws[WS_XMAX] = red[0] + 10.0f;
    } else {
        int i = (bid - 2) * 256 + tid;
        if (i < B_N) out[i] = 0.0f;
    }
}

// ---------------- hpart precompute: [16384][128] fp32 into ws ---------------
// 512 blocks x 32 b-rows. Stage W1 (33KB, padded) + all 32 h rows (8KB) once,
// ONE sync, then 16 independent outputs/thread. ~4 us.
__launch_bounds__(256)
__global__ void umnn_hpart(const float* __restrict__ h, const float* __restrict__ W1,
                           const float* __restrict__ b1, float* __restrict__ ws)
{
    __shared__ float W1s[HD][IND + 1];
    __shared__ float hsh[32 * (IND - 1)];
    float* hpartG = ws + WS_HPART;
    const int tid = threadIdx.x;
    const int b32 = blockIdx.x * 32;

    for (int i = tid; i < HD * IND / 4; i += 256) {
        float4 v = ((const float4*)W1)[i];
        int r = i >> 4, c = (i & 15) * 4;
        W1s[r][c] = v.x; W1s[r][c + 1] = v.y; W1s[r][c + 2] = v.z; W1s[r][c + 3] = v.w;
    }
    for (int i = tid; i < 32 * (IND - 1); i += 256)
        hsh[i] = h[b32 * (IND - 1) + i];
    __syncthreads();

    const int n = tid & 127, bloc = tid >> 7;
    const float b1v = b1[n];
    #pragma unroll 2
    for (int it = 0; it < 16; ++it) {
        int r = it * 2 + bloc;
        const float* hr = hsh + r * (IND - 1);
        float acc = b1v;
        #pragma unroll
        for (int d = 0; d < IND - 1; ++d)
            acc = fmaf(W1s[n][1 + d], hr[d], acc);
        hpartG[(b32 + r) * HD + n] = acc;
    }
}

// ---------------- main MFMA kernel ------------------------------------------
template<bool HPG>
__launch_bounds__(256, 3)
__global__ void umnn_main(const float* __restrict__ x,  const float* __restrict__ h,
                          const float* __restrict__ W1, const float* __restrict__ b1,
                          const float* __restrict__ W2, const float* __restrict__ b2,
                          const float* __restrict__ W3, const float* __restrict__ b3,
                          const float* __restrict__ W4, const float* __restrict__ b4,
                          float* __restrict__ out, const float* __restrict__ ws)
{
    __shared__ __align__(16) char  y1s[TS * 256];   // 64 rows x 128 bf16, swizzled
    __shared__ __align__(16) char  y2s[TS * 256];
    __shared__ float partS4[4][TS];                 // per-wave layer4 partials
    __shared__ __align__(16) float hpS[3 * HD];     // fallback path only
    __shared__ float sSteps[64], sCcw[64];

    const int tid  = threadIdx.x;
    const int w    = tid >> 6;
    const int lane = tid & 63;
    const int q    = lane >> 4;
    const int lm   = lane & 15;
    const int swz  = lm & 7;
    const int n8   = tid & 15;          // phase-A feature octet: n8*8 .. n8*8+7
    const int ms   = tid >> 4;          // phase-A sample: ms + 16*it

    if (tid < KQ) { sSteps[tid] = ws[WS_STEPS + tid]; sCcw[tid] = ws[WS_CCW + tid]; }

    const float xmax = ws[WS_XMAX];
    const float b4v  = b4[0];

    // phase-A W1 x-column slice (8 features)
    float w1x[8];
    #pragma unroll
    for (int j = 0; j < 8; ++j) w1x[j] = W1[(n8 * 8 + j) * IND];

    // wave-resident weight A-frags + per-lane bias/W4 slices
    short8 W2A[2][4], W3A[2][4];
    f32x4  b2r[2], b3r[2], W4r[2];
    #pragma unroll
    for (int ntl = 0; ntl < 2; ++ntl) {
        const int nf = (w * 2 + ntl) * 16 + lm;
        #pragma unroll
        for (int kk = 0; kk < 4; ++kk) {
            const float* p2 = W2 + nf * HD + kk * 32 + q * 8;
            const float* p3 = W3 + nf * HD + kk * 32 + q * 8;
            short8 a2, a3;
            #pragma unroll
            for (int j = 0; j < 8; ++j) {
                a2[j] = (short)f2bf(p2[j]);
                a3[j] = (short)f2bf(p3[j]);
            }
            W2A[ntl][kk] = a2; W3A[ntl][kk] = a3;
        }
        const int nb0 = (w * 2 + ntl) * 16 + q * 4;
        b2r[ntl] = *(const f32x4*)(b2 + nb0);
        b3r[ntl] = *(const f32x4*)(b3 + nb0);
        W4r[ntl] = *(const f32x4*)(W4 + nb0);
    }
    __syncthreads();                                   // sSteps/sCcw ready

    for (int tile = blockIdx.x; tile < NTILES; tile += GRID_MAIN) {
        const int g0 = tile * TS;
        const int b0 = g0 / KQ;
        const float* hpB;
        if (HPG) {
            hpB = ws + WS_HPART + b0 * HD + n8 * 8;
        } else {
            const int nb = (g0 + TS - 1) / KQ - b0 + 1;
            for (int idx = tid; idx < nb * HD; idx += 256) {
                int r = idx >> 7, n = idx & 127;
                const float* hr = h + (b0 + r) * (IND - 1);
                const float* wr = W1 + n * IND + 1;
                float acc = b1[n];
                #pragma unroll
                for (int d = 0; d < IND - 1; ++d) acc = fmaf(wr[d], hr[d], acc);
                hpS[idx] = acc;
            }
            __syncthreads();
            hpB = hpS + n8 * 8;
        }

        // ---- phase A: Y1 -> LDS (bf16, sample-major, swizzled b128 stores) ----
        {
            const int phys = (n8 ^ (ms & 7)) << 4;     // swizzle const per thread
            #pragma unroll
            for (int it = 0; it < 4; ++it) {
                int m  = ms + it * 16;
                int g  = g0 + m;
                int bb = (int)((unsigned)g / KQ);
                float x0 = x[bb];
                float X  = fmaf((xmax - x0) * 0.5f, sSteps[g - bb * KQ] + 1.0f, x0);
                const float* hp = hpB + (bb - b0) * HD;
                f32x4 ha = *(const f32x4*)hp;
                f32x4 hb = *(const f32x4*)(hp + 4);
                unsigned u0 = pk_bf16(fmaxf(fmaf(X, w1x[0], ha[0]), 0.f),
                                      fmaxf(fmaf(X, w1x[1], ha[1]), 0.f));
                unsigned u1 = pk_bf16(fmaxf(fmaf(X, w1x[2], ha[2]), 0.f),
                                      fmaxf(fmaf(X, w1x[3], ha[3]), 0.f));
                unsigned u2 = pk_bf16(fmaxf(fmaf(X, w1x[4], hb[0]), 0.f),
                                      fmaxf(fmaf(X, w1x[5], hb[1]), 0.f));
                unsigned u3 = pk_bf16(fmaxf(fmaf(X, w1x[6], hb[2]), 0.f),
                                      fmaxf(fmaf(X, w1x[7], hb[3]), 0.f));
                *(int4*)(y1s + m * 256 + phys) = make_int4(u0, u1, u2, u3);
            }
        }
        __syncthreads();                               // S3: y1 ready

        // ---- layer 2: C = W2(A,reg) x Y1(B,LDS) + b2 ----
        f32x4 C[2][4];
        #pragma unroll
        for (int ntl = 0; ntl < 2; ++ntl)
            #pragma unroll
            for (int mt = 0; mt < 4; ++mt) C[ntl][mt] = b2r[ntl];
        #pragma unroll
        for (int kk = 0; kk < 4; ++kk)
            #pragma unroll
            for (int mt = 0; mt < 4; ++mt) {
                short8 Bf = *(const short8*)(y1s + (mt * 16 + lm) * 256
                                             + ((((kk << 2) + q) ^ swz) << 4));
                C[0][mt] = __builtin_amdgcn_mfma_f32_16x16x32_bf16(W2A[0][kk], Bf, C[0][mt], 0, 0, 0);
                C[1][mt] = __builtin_amdgcn_mfma_f32_16x16x32_bf16(W2A[1][kk], Bf, C[1][mt], 0, 0, 0);
            }
        // write Y2 = bf16(relu(C)) packed b64, sample-major
        #pragma unroll
        for (int ntl = 0; ntl < 2; ++ntl) {
            const int cch  = ((w * 2 + ntl) << 1) + (q >> 1);
            const int off8 = (q & 1) << 3;
            #pragma unroll
            for (int mt = 0; mt < 4; ++mt) {
                f32x4 v = C[ntl][mt];
                unsigned lo = pk_bf16(fmaxf(v[0], 0.f), fmaxf(v[1], 0.f));
                unsigned hi = pk_bf16(fmaxf(v[2], 0.f), fmaxf(v[3], 0.f));
                *(int2*)(y2s + (mt * 16 + lm) * 256 + ((cch ^ swz) << 4) + off8)
                    = make_int2((int)lo, (int)hi);
            }
        }
        __syncthreads();                               // S4: y2 ready

        // ---- layer 3: C = W3(A,reg) x Y2(B,LDS) + b3 ----
        #pragma unroll
        for (int ntl = 0; ntl < 2; ++ntl)
            #pragma unroll
            for (int mt = 0; mt < 4; ++mt) C[ntl][mt] = b3r[ntl];
        #pragma unroll
        for (int kk = 0; kk < 4; ++kk)
            #pragma unroll
            for (int mt = 0; mt < 4; ++mt) {
                short8 Bf = *(const short8*)(y2s + (mt * 16 + lm) * 256
                                             + ((((kk << 2) + q) ^ swz) << 4));
                C[0][mt] = __builtin_amdgcn_mfma_f32_16x16x32_bf16(W3A[0][kk], Bf, C[0][mt], 0, 0, 0);
                C[1][mt] = __builtin_amdgcn_mfma_f32_16x16x32_bf16(W3A[1][kk], Bf, C[1][mt], 0, 0, 0);
            }

        // ---- layer 4 partials: pm = sum relu(y3)*W4 over wave's 32 features ----
        #pragma unroll
        for (int mt = 0; mt < 4; ++mt) {
            float p = 0.f;
            #pragma unroll
            for (int ntl = 0; ntl < 2; ++ntl) {
                f32x4 v = C[ntl][mt];
                p = fmaf(fmaxf(v[0], 0.f), W4r[ntl][0], p);
                p = fmaf(fmaxf(v[1], 0.f), W4r[ntl][1], p);
                p = fmaf(fmaxf(v[2], 0.f), W4r[ntl][2], p);
                p = fmaf(fmaxf(v[3], 0.f), W4r[ntl][3], p);
            }
            p += __shfl_xor(p, 16);
            p += __shfl_xor(p, 32);
            if (lane < 16) partS4[w][mt * 16 + lane] = p;
        }
        __syncthreads();                               // S5: partials ready

        if (tid < TS) {
            int g  = g0 + tid;
            int bb = (int)((unsigned)g / KQ);
            int k  = g - bb * KQ;
            float x0 = x[bb];
            float y4 = partS4[0][tid] + partS4[1][tid] + partS4[2][tid]
                     + partS4[3][tid] + b4v;
            float f  = (y4 > 0.f) ? (y4 + 1.f) : __expf(y4);
            atomicAdd(&out[bb], f * (sCcw[k] * (xmax - x0) * 0.5f));
        }
        // next-tile phase A may start: y1s readers done at S4, partS4 next
        // written only after next S4, y2s next written after next S3. Safe.
    }
}

// ---------------------------------------------------------------------------
extern "C" void kernel_launch(void* const* d_in, const int* in_sizes, int n_in,
                              void* d_out, int out_size, void* d_ws, size_t ws_size,
                              hipStream_t stream)
{
    const float* x  = (const float*)d_in[0];
    const float* h  = (const float*)d_in[1];
    const float* W1 = (const float*)d_in[2];
    const float* b1 = (const float*)d_in[3];
    const float* W2 = (const float*)d_in[4];
    const float* b2 = (const float*)d_in[5];
    const float* W3 = (const float*)d_in[6];
    const float* b3 = (const float*)d_in[7];
    const float* W4 = (const float*)d_in[8];
    const float* b4 = (const float*)d_in[9];
    float* out = (float*)d_out;
    float* ws  = (float*)d_ws;

    umnn_prep<<<2 + (B_N + 255) / 256, 256, 0, stream>>>(x, out, ws);

    const size_t need = (size_t)(WS_HPART + B_N * HD) * sizeof(float);
    if (ws_size >= need) {
        umnn_hpart<<<512, 256, 0, stream>>>(h, W1, b1, ws);
        umnn_main<true><<<GRID_MAIN, 256, 0, stream>>>(x, h, W1, b1, W2, b2, W3, b3,
                                                       W4, b4, out, ws);
    } else {
        umnn_main<false><<<GRID_MAIN, 256, 0, stream>>>(x, h, W1, b1, W2, b2, W3, b3,
                                                        W4, b4, out, ws);
    }
}